// Round 1
// 546.623 us; speedup vs baseline: 1.0467x; 1.0467x over previous
//
#include <hip/hip_runtime.h>
#include <math.h>

#define BB 32
#define LL 512
#define DD 512
#define NH 8
#define HD 64

typedef __attribute__((ext_vector_type(8))) short bf16x8;
typedef __attribute__((ext_vector_type(4))) float f32x4;

__device__ __forceinline__ unsigned short f2bf(float x) {
    union { float f; unsigned u; } v; v.f = x;
    unsigned r = v.u + 0x7fffu + ((v.u >> 16) & 1u);  // RNE
    return (unsigned short)(r >> 16);
}

// ---------------- reductions ----------------
__device__ __forceinline__ float warp_sum(float v) {
    #pragma unroll
    for (int o = 32; o > 0; o >>= 1) v += __shfl_down(v, o);
    return v;
}

// ---------------- LayerNorm: one block per row of 512, bf16 out ----------------
__global__ void ln_kernel(const float* __restrict__ X, const float* __restrict__ g,
                          const float* __restrict__ b, unsigned short* __restrict__ Y) {
    __shared__ float red[8];
    const size_t base = (size_t)blockIdx.x * DD;
    const int t = threadIdx.x;
    float x0 = X[base + t], x1 = X[base + t + 256];
    float s = warp_sum(x0 + x1);
    float q = warp_sum(x0 * x0 + x1 * x1);
    if ((t & 63) == 0) { red[t >> 6] = s; red[4 + (t >> 6)] = q; }
    __syncthreads();
    float S = red[0] + red[1] + red[2] + red[3];
    float Q = red[4] + red[5] + red[6] + red[7];
    float mu  = S * (1.0f / 512.0f);
    float var = Q * (1.0f / 512.0f) - mu * mu;
    float r = rsqrtf(var + 1e-5f);
    Y[base + t]       = f2bf((x0 - mu) * r * g[t] + b[t]);
    Y[base + t + 256] = f2bf((x1 - mu) * r * g[t + 256] + b[t + 256]);
}

// ---------------- weight transpose + bf16 cast: W (K x N) -> WT (N x K) ----------------
__global__ void transpose_bf16(const float* __restrict__ W, unsigned short* __restrict__ WT,
                               int K, int N) {
    __shared__ float t[32][33];
    const int n0 = blockIdx.x * 32, k0 = blockIdx.y * 32;
    const int tx = threadIdx.x & 31, ty = threadIdx.x >> 5;
    #pragma unroll
    for (int r = 0; r < 32; r += 8)
        t[ty + r][tx] = W[(size_t)(k0 + ty + r) * N + n0 + tx];
    __syncthreads();
    #pragma unroll
    for (int r = 0; r < 32; r += 8)
        WT[(size_t)(n0 + ty + r) * K + k0 + tx] = f2bf(t[tx][ty + r]);
}

// ---------------- bf16 MFMA GEMM ----------------
// A: M x K bf16 row-major; BT: N x K bf16 row-major. 128x128 tile, BK=64.
// OM: 0 = f32 out, 1 = bf16 out,
//     2 = qkv split: Q -> Cv row-major [row][512]; K -> kfrag blobs; V -> vfrag blobs.
// Fragment blob layout (1 KB each): idx [b][h][kt][kk][j], element (lane*8 + e)
//   K: lane=hi*16+lo holds K[kpos=kt*64+j*16+lo][d=kk*32+hi*8+e]
//   V: lane=hi*16+lo holds V[d=j*16+lo][kpos=kt*64+kk*32+hi*8+e]
template <int ACT, int RES, int OM>
__global__ __launch_bounds__(256)
void gemm_mfma(const unsigned short* __restrict__ A, const unsigned short* __restrict__ BT,
               const float* __restrict__ bias, const float* __restrict__ res,
               void* __restrict__ Cv, unsigned short* __restrict__ kfrag,
               unsigned short* __restrict__ vfrag, int M, int N, int K) {
    __shared__ unsigned short As[128 * 64];
    __shared__ unsigned short Bs[128 * 64];
    const int tid = threadIdx.x;
    const int wave = tid >> 6, lane = tid & 63;
    const int wm = (wave >> 1) * 64, wn = (wave & 1) * 64;
    const int bm = blockIdx.y * 128, bn = blockIdx.x * 128;

    f32x4 acc[4][4] = {};

    for (int k0 = 0; k0 < K; k0 += 64) {
        __syncthreads();
        #pragma unroll
        for (int it = 0; it < 4; ++it) {
            const int s = it * 256 + tid;
            const int row = s >> 3, pch = s & 7;
            const int lch = pch ^ (row & 7);
            const unsigned short* ga = A + (size_t)(bm + row) * K + k0 + lch * 8;
            __builtin_amdgcn_global_load_lds(
                (const __attribute__((address_space(1))) void*)ga,
                (__attribute__((address_space(3))) void*)(As + s * 8), 16, 0, 0);
            const unsigned short* gb = BT + (size_t)(bn + row) * K + k0 + lch * 8;
            __builtin_amdgcn_global_load_lds(
                (const __attribute__((address_space(1))) void*)gb,
                (__attribute__((address_space(3))) void*)(Bs + s * 8), 16, 0, 0);
        }
        __syncthreads();
        #pragma unroll
        for (int ks = 0; ks < 2; ++ks) {
            bf16x8 af[4], bfr[4];
            #pragma unroll
            for (int i = 0; i < 4; ++i) {
                const int row = wm + i * 16 + (lane & 15);
                const int pch = (ks * 4 + (lane >> 4)) ^ (row & 7);
                af[i] = *(const bf16x8*)(As + row * 64 + pch * 8);
            }
            #pragma unroll
            for (int j = 0; j < 4; ++j) {
                const int row = wn + j * 16 + (lane & 15);
                const int pch = (ks * 4 + (lane >> 4)) ^ (row & 7);
                bfr[j] = *(const bf16x8*)(Bs + row * 64 + pch * 8);
            }
            #pragma unroll
            for (int i = 0; i < 4; ++i)
                #pragma unroll
                for (int j = 0; j < 4; ++j)
                    acc[i][j] = __builtin_amdgcn_mfma_f32_16x16x32_bf16(
                        af[i], bfr[j], acc[i][j], 0, 0, 0);
        }
    }

    const int cl = lane & 15, rq = (lane >> 4) * 4;
    #pragma unroll
    for (int j = 0; j < 4; ++j) {
        const int col = bn + wn + j * 16 + cl;
        const float bv = bias[col];
        #pragma unroll
        for (int i = 0; i < 4; ++i) {
            const int r0 = bm + wm + i * 16 + rq;
            #pragma unroll
            for (int r = 0; r < 4; ++r) {
                float v = acc[i][j][r] + bv;
                if (ACT == 1) v = 0.5f * v * (1.0f + erff(v * 0.70710678118654752f));
                if (RES) v += res[(size_t)(r0 + r) * N + col];
                if (OM == 0) {
                    ((float*)Cv)[(size_t)(r0 + r) * N + col] = v;
                } else if (OM == 1) {
                    ((unsigned short*)Cv)[(size_t)(r0 + r) * N + col] = f2bf(v);
                } else {
                    const int row = r0 + r;
                    const int b = row >> 9, kpos = row & 511;
                    if (col < 512) {
                        ((unsigned short*)Cv)[(size_t)row * 512 + col] = f2bf(v);
                    } else if (col < 1024) {
                        const int h = (col - 512) >> 6, dd = (col - 512) & 63;
                        const int kt = kpos >> 6, jj = (kpos >> 4) & 3, lo2 = kpos & 15;
                        const int kk = dd >> 5, hi2 = (dd >> 3) & 3, e = dd & 7;
                        kfrag[((((size_t)(b * NH + h) * 8 + kt) * 2 + kk) * 4 + jj) * 512
                              + (hi2 * 16 + lo2) * 8 + e] = f2bf(v);
                    } else {
                        const int h = (col - 1024) >> 6, dd = (col - 1024) & 63;
                        const int kt = kpos >> 6, kk = (kpos >> 5) & 1, hi2 = (kpos >> 3) & 3, e = kpos & 7;
                        const int jj = dd >> 4, lo2 = dd & 15;
                        vfrag[((((size_t)(b * NH + h) * 8 + kt) * 2 + kk) * 4 + jj) * 512
                              + (hi2 * 16 + lo2) * 8 + e] = f2bf(v);
                    }
                }
            }
        }
    }
}

// ---------------- fused flash attention v2, all heads per block ----------------
// grid: (qg=32, b=32), 512 threads = 8 waves; wave w = head w.
// v2 changes (v1 was serialization-bound: MfmaUtil 5%, VALU 29%, HBM 22%):
//  - swapped QK^T: s = mfma(K, Q). A/B fragment lane layouts coincide for
//    16x16x32 bf16, so kfrag/Q blobs are reused unchanged; each lane now owns
//    one q-row (q = lane&15) of P across k. Softmax row-reduce = in-register
//    tree + 2 shuffles (was 4+4 dependent shuffles over 16 lanes).
//  - inter tile staged global->reg early / ds_write late (T14), into two
//    DISTINCT __shared__ buffers (it0/it1) so stage writes provably don't
//    alias bias reads -> no conservative vmcnt drain in the consume path.
//  - load issue order pinned with sched_barrier: kf -> (compute) -> vf ->
//    inter-next; every consumer's counted vmcnt leaves later loads in flight.
//  - P roundtrip: 4 packed b64 stores (was 16 u16 stores).
//  - inter tile row stride 260 floats keeps the new read pattern bank-uniform.
__global__ __launch_bounds__(512)
void flash_kernel(const unsigned short* __restrict__ qbuf,
                  const unsigned short* __restrict__ kfrag,
                  const unsigned short* __restrict__ vfrag,
                  const float* __restrict__ inter,
                  const float* __restrict__ iw,
                  unsigned short* __restrict__ O) {
    __shared__ float it0[16 * 260];                 // inter tile buffer A (pad 256->260)
    __shared__ float it1[16 * 260];                 // inter tile buffer B
    __shared__ unsigned short plds[8][16 * 72];     // per-wave P tile
    const int qg = blockIdx.x, b = blockIdx.y;
    const int tid = threadIdx.x, wave = tid >> 6, lane = tid & 63;
    const int h = wave;
    const int lo = lane & 15, hi = lane >> 4;

    const float iw0 = iw[h], iw1 = iw[8 + h], iw2 = iw[16 + h], iw3 = iw[24 + h];
    const float* interb = inter + (size_t)b * 512 * 512 * 4;
    unsigned short* pw = &plds[wave][0];

    // Q fragment (fixed for whole block): row/col = lo, d = kk*32 + hi*8 + e
    const unsigned short* qp = qbuf + ((size_t)(b * 512 + qg * 16 + lo)) * 512 + h * 64 + hi * 8;
    const bf16x8 qf0 = *(const bf16x8*)(qp);
    const bf16x8 qf1 = *(const bf16x8*)(qp + 32);

    // per-wave staging rows (wave w owns q-local rows 2w, 2w+1)
    const int srow = wave * 2;
    const float* src0 = interb + ((size_t)(qg * 16 + srow) * 512) * 4 + lane * 4;
    const float* src1 = interb + ((size_t)(qg * 16 + srow + 1) * 512) * 4 + lane * 4;

    f32x4 o[4] = {};
    float m = -1e30f, lsum = 0.0f;

    // prologue: stage tile 0 (reg -> LDS)
    {
        const float4 a0 = *(const float4*)src0;
        const float4 a1 = *(const float4*)src1;
        *(float4*)(it0 + srow * 260 + lane * 4) = a0;
        *(float4*)(it0 + (srow + 1) * 260 + lane * 4) = a1;
    }

    auto iter = [&](int kt, const float* __restrict__ rd, float* __restrict__ st) {
        const size_t fb = (((size_t)((b * NH + h) * 8 + kt)) * 2) * 4 * 512;
        __syncthreads();  // rd valid for all waves; st free to overwrite
        // (1) K fragments first (8 x 1KB lane-contiguous, mostly L2-hit)
        bf16x8 kf0[4], kf1[4];
        #pragma unroll
        for (int j = 0; j < 4; ++j)
            kf0[j] = *(const bf16x8*)(kfrag + fb + (size_t)j * 512 + lane * 8);
        #pragma unroll
        for (int j = 0; j < 4; ++j)
            kf1[j] = *(const bf16x8*)(kfrag + fb + (size_t)(4 + j) * 512 + lane * 8);
        __builtin_amdgcn_sched_barrier(0);
        // (2) S^T = K Q^T : lane owns q = lo, k = j*16 + hi*4 + r
        f32x4 s[4] = {};
        __builtin_amdgcn_s_setprio(1);
        #pragma unroll
        for (int j = 0; j < 4; ++j)
            s[j] = __builtin_amdgcn_mfma_f32_16x16x32_bf16(kf0[j], qf0, s[j], 0, 0, 0);
        #pragma unroll
        for (int j = 0; j < 4; ++j)
            s[j] = __builtin_amdgcn_mfma_f32_16x16x32_bf16(kf1[j], qf1, s[j], 0, 0, 0);
        __builtin_amdgcn_s_setprio(0);
        // (3) bias + scale from LDS (bank-uniform via 260 stride)
        const float4* brow = (const float4*)(rd + lo * 260);
        #pragma unroll
        for (int j = 0; j < 4; ++j)
            #pragma unroll
            for (int r = 0; r < 4; ++r) {
                const float4 f = brow[j * 16 + hi * 4 + r];
                s[j][r] = s[j][r] * 0.125f + f.x * iw0 + f.y * iw1 + f.z * iw2 + f.w * iw3;
            }
        // (4) V fragments (latency hidden under softmax)
        bf16x8 vf0[4], vf1[4];
        #pragma unroll
        for (int j = 0; j < 4; ++j)
            vf0[j] = *(const bf16x8*)(vfrag + fb + (size_t)j * 512 + lane * 8);
        #pragma unroll
        for (int j = 0; j < 4; ++j)
            vf1[j] = *(const bf16x8*)(vfrag + fb + (size_t)(4 + j) * 512 + lane * 8);
        __builtin_amdgcn_sched_barrier(0);
        // (5) inter tile kt+1: global -> regs, issued LAST so PV's vf-wait
        //     (vmcnt(2)) leaves these in flight until the ds_write at the end.
        float4 sn0, sn1;
        if (kt < 7) {
            sn0 = *(const float4*)(src0 + (kt + 1) * 256);
            sn1 = *(const float4*)(src1 + (kt + 1) * 256);
        }
        __builtin_amdgcn_sched_barrier(0);
        // (6) online softmax, per-lane row q = lo (replicated over hi groups)
        float t0 = fmaxf(fmaxf(s[0][0], s[0][1]), fmaxf(s[0][2], s[0][3]));
        float t1 = fmaxf(fmaxf(s[1][0], s[1][1]), fmaxf(s[1][2], s[1][3]));
        float t2 = fmaxf(fmaxf(s[2][0], s[2][1]), fmaxf(s[2][2], s[2][3]));
        float t3 = fmaxf(fmaxf(s[3][0], s[3][1]), fmaxf(s[3][2], s[3][3]));
        float mx = fmaxf(fmaxf(t0, t1), fmaxf(t2, t3));
        mx = fmaxf(mx, __shfl_xor(mx, 16));
        mx = fmaxf(mx, __shfl_xor(mx, 32));
        const float mn = fmaxf(m, mx);
        const float al = __expf(m - mn);
        m = mn;
        #pragma unroll
        for (int j = 0; j < 4; ++j)
            #pragma unroll
            for (int r = 0; r < 4; ++r)
                s[j][r] = __expf(s[j][r] - mn);
        float u0 = (s[0][0] + s[0][1]) + (s[0][2] + s[0][3]);
        float u1 = (s[1][0] + s[1][1]) + (s[1][2] + s[1][3]);
        float u2 = (s[2][0] + s[2][1]) + (s[2][2] + s[2][3]);
        float u3 = (s[3][0] + s[3][1]) + (s[3][2] + s[3][3]);
        float ts = (u0 + u1) + (u2 + u3);
        ts += __shfl_xor(ts, 16);
        ts += __shfl_xor(ts, 32);
        lsum = lsum * al + ts;
        // (7) redistribute alpha to C-layout rows (q = hi*4 + r), independent shuffles
        const float aR0 = __shfl(al, hi * 4 + 0);
        const float aR1 = __shfl(al, hi * 4 + 1);
        const float aR2 = __shfl(al, hi * 4 + 2);
        const float aR3 = __shfl(al, hi * 4 + 3);
        #pragma unroll
        for (int j2 = 0; j2 < 4; ++j2) {
            o[j2][0] *= aR0; o[j2][1] *= aR1; o[j2][2] *= aR2; o[j2][3] *= aR3;
        }
        // (8) P -> LDS, packed b64, wave-private (no barrier)
        uint2* pq = (uint2*)(pw + lo * 72);
        #pragma unroll
        for (int j = 0; j < 4; ++j) {
            uint2 d;
            d.x = (unsigned)f2bf(s[j][0]) | ((unsigned)f2bf(s[j][1]) << 16);
            d.y = (unsigned)f2bf(s[j][2]) | ((unsigned)f2bf(s[j][3]) << 16);
            pq[j * 4 + hi] = d;
        }
        // (9) O += P V
        __builtin_amdgcn_s_setprio(1);
        #pragma unroll
        for (int kk = 0; kk < 2; ++kk) {
            const bf16x8 pf = *(const bf16x8*)(pw + lo * 72 + kk * 32 + hi * 8);
            #pragma unroll
            for (int j2 = 0; j2 < 4; ++j2)
                o[j2] = __builtin_amdgcn_mfma_f32_16x16x32_bf16(
                    pf, kk ? vf1[j2] : vf0[j2], o[j2], 0, 0, 0);
        }
        __builtin_amdgcn_s_setprio(0);
        // (10) write inter tile kt+1 (vmcnt drains sn here, end of iteration)
        if (kt < 7) {
            *(float4*)(st + srow * 260 + lane * 4) = sn0;
            *(float4*)(st + (srow + 1) * 260 + lane * 4) = sn1;
        }
    };

    for (int kt2 = 0; kt2 < 4; ++kt2) {
        iter(kt2 * 2, it0, it1);
        iter(kt2 * 2 + 1, it1, it0);
    }

    // ---- epilogue ----
    const float iR0 = 1.0f / __shfl(lsum, hi * 4 + 0);
    const float iR1 = 1.0f / __shfl(lsum, hi * 4 + 1);
    const float iR2 = 1.0f / __shfl(lsum, hi * 4 + 2);
    const float iR3 = 1.0f / __shfl(lsum, hi * 4 + 3);
    const int qC0 = qg * 16 + hi * 4;
    #pragma unroll
    for (int j2 = 0; j2 < 4; ++j2) {
        O[(size_t)(b * 512 + qC0 + 0) * 512 + h * 64 + j2 * 16 + lo] = f2bf(o[j2][0] * iR0);
        O[(size_t)(b * 512 + qC0 + 1) * 512 + h * 64 + j2 * 16 + lo] = f2bf(o[j2][1] * iR1);
        O[(size_t)(b * 512 + qC0 + 2) * 512 + h * 64 + j2 * 16 + lo] = f2bf(o[j2][2] * iR2);
        O[(size_t)(b * 512 + qC0 + 3) * 512 + h * 64 + j2 * 16 + lo] = f2bf(o[j2][3] * iR3);
    }
}

// ---------------- launch ----------------
extern "C" void kernel_launch(void* const* d_in, const int* in_sizes, int n_in,
                              void* d_out, int out_size, void* d_ws, size_t ws_size,
                              hipStream_t stream) {
    const float* x     = (const float*)d_in[0];
    const float* inter = (const float*)d_in[1];
    const float* qkv_w = (const float*)d_in[2];
    const float* qkv_b = (const float*)d_in[3];
    const float* out_w = (const float*)d_in[4];
    const float* out_b = (const float*)d_in[5];
    const float* n1g   = (const float*)d_in[6];
    const float* n1b   = (const float*)d_in[7];
    const float* n2g   = (const float*)d_in[8];
    const float* n2b   = (const float*)d_in[9];
    const float* iw    = (const float*)d_in[10];
    const float* fw1   = (const float*)d_in[11];
    const float* fb1   = (const float*)d_in[12];
    const float* fw2   = (const float*)d_in[13];
    const float* fb2   = (const float*)d_in[14];
    float* out = (float*)d_out;

    // workspace layout (bytes): total 190,840,832
    //   qbuf    @ 0           : 16,777,216  (16384 x 512 bf16 Q)
    //   kfrag   @ 16777216    : 16,777,216  (fragment blobs)
    //   vfrag   @ 33554432    : 16,777,216  (fragment blobs)
    //   attnout @ 50331648    : 16,777,216
    //   x2      @ 67108864    : 33,554,432  (fp32)
    //   h_bf    @ 100663296   : 16,777,216
    //   ffnmid  @ 117440512   : 67,108,864
    //   weights @ 184549376   : ~6.3 MB
    if (ws_size < 190840832ull) return;
    char* ws = (char*)d_ws;
    unsigned short* qbuf    = (unsigned short*)(ws);
    unsigned short* kfrag   = (unsigned short*)(ws + 16777216ull);
    unsigned short* vfrag   = (unsigned short*)(ws + 33554432ull);
    unsigned short* attnout = (unsigned short*)(ws + 50331648ull);
    float*          x2      = (float*)(ws + 67108864ull);
    unsigned short* h_bf    = (unsigned short*)(ws + 100663296ull);
    unsigned short* ffnmid  = (unsigned short*)(ws + 117440512ull);
    unsigned short* qkv_wT  = (unsigned short*)(ws + 184549376ull);
    unsigned short* out_wT  = (unsigned short*)(ws + 186122240ull);
    unsigned short* fw1T    = (unsigned short*)(ws + 186646528ull);
    unsigned short* fw2T    = (unsigned short*)(ws + 188743680ull);

    const int M = BB * LL;  // 16384

    // 0. weight transposes -> bf16 B^T
    transpose_bf16<<<dim3(1536 / 32, 512 / 32), 256, 0, stream>>>(qkv_w, qkv_wT, 512, 1536);
    transpose_bf16<<<dim3(512 / 32, 512 / 32), 256, 0, stream>>>(out_w, out_wT, 512, 512);
    transpose_bf16<<<dim3(2048 / 32, 512 / 32), 256, 0, stream>>>(fw1, fw1T, 512, 2048);
    transpose_bf16<<<dim3(512 / 32, 2048 / 32), 256, 0, stream>>>(fw2, fw2T, 2048, 512);
    // 1. LN1: x -> h_bf
    ln_kernel<<<M, 256, 0, stream>>>(x, n1g, n1b, h_bf);
    // 2. qkv GEMM -> qbuf + kfrag + vfrag (fragment-packed K/V)
    gemm_mfma<0, 0, 2><<<dim3(1536 / 128, M / 128), 256, 0, stream>>>(
        h_bf, qkv_wT, qkv_b, nullptr, qbuf, kfrag, vfrag, M, 1536, 512);
    // 3. fused flash attention
    flash_kernel<<<dim3(LL / 16, BB), 512, 0, stream>>>(qbuf, kfrag, vfrag, inter, iw, attnout);
    // 4. x2 = x + attnout @ out_w + out_b
    gemm_mfma<0, 1, 0><<<dim3(512 / 128, M / 128), 256, 0, stream>>>(
        attnout, out_wT, out_b, x, x2, nullptr, nullptr, M, 512, 512);
    // 5. LN2: x2 -> h_bf
    ln_kernel<<<M, 256, 0, stream>>>(x2, n2g, n2b, h_bf);
    // 6. ffnmid = gelu(h2 @ fw1 + fb1) -> bf16
    gemm_mfma<1, 0, 1><<<dim3(2048 / 128, M / 128), 256, 0, stream>>>(
        h_bf, fw1T, fb1, nullptr, ffnmid, nullptr, nullptr, M, 2048, 512);
    // 7. out = x2 + ffnmid @ fw2 + fb2
    gemm_mfma<0, 1, 0><<<dim3(512 / 128, M / 128), 256, 0, stream>>>(
        ffnmid, fw2T, fb2, x2, out, nullptr, nullptr, M, 512, 2048);
}